// Round 15
// baseline (429.643 us; speedup 1.0000x reference)
//
#include <hip/hip_runtime.h>
#include <stdint.h>

// RBM CD-4, fused single kernel. R15 = R14's i8 math on R9's 1024-block geometry,
// with the cap-128 launch_bounds that provably fits (R9 failed ONLY by its cap-64).
// R14 post-mortem: occupancy 42% was GRID-limited (512 blocks = 2/CU; VGPR 64 would
// allow 32 waves/CU). 1024 blocks x 16 rows -> 4 blocks/CU, up to 32 waves/CU.
// Rows: lr<8 -> bt8+lr ; lr>=8 -> 8192+bt8+(lr-8). Pair (lr, lr+8) sits in lanes
// l15/l15+8 and shares each 32-bit counter hash (lo16/hi16).
// h-pass: j split 8 ways (16 j/wave), K=4096 via 32 c-iters x 2 i8 MFMAs (2 chains),
// direct WHq loads (W L2-resident). x-pass: d split 8 ways (512 d/wave), direct WXq
// loads, hash-share via shfl_xor(.,8), no in-loop barriers.
// RNG: lowbias32 counter hash; sample via fma(h,q,h) < 65536.
// ws: [WHq 512KB][WXq 512KB][S 2 doubles]

#define BB 16384
#define DD 4096
#define HH 128

typedef float    f32x4 __attribute__((ext_vector_type(4)));
typedef int      i32x4 __attribute__((ext_vector_type(4)));
typedef uint32_t u32x4 __attribute__((ext_vector_type(4)));

struct RbmKeys { uint32_t kh[4]; uint32_t kx[4]; };

// host-only: threefry for key derivation
static void tf2x32_host(uint32_t k0, uint32_t k1, uint32_t x0, uint32_t x1,
                        uint32_t& o0, uint32_t& o1) {
  uint32_t ks2 = k0 ^ k1 ^ 0x1BD11BDAu;
  x0 += k0; x1 += k1;
#define TFR(r) { x0 += x1; x1 = (x1 << (r)) | (x1 >> (32 - (r))); x1 ^= x0; }
  TFR(13) TFR(15) TFR(26) TFR(6)
  x0 += k1; x1 += ks2 + 1u;
  TFR(17) TFR(29) TFR(16) TFR(24)
  x0 += ks2; x1 += k0 + 2u;
  TFR(13) TFR(15) TFR(26) TFR(6)
  x0 += k0; x1 += k1 + 3u;
  TFR(17) TFR(29) TFR(16) TFR(24)
  x0 += k1; x1 += ks2 + 4u;
  TFR(13) TFR(15) TFR(26) TFR(6)
  x0 += ks2; x1 += k0 + 5u;
#undef TFR
  o0 = x0; o1 = x1;
}

__device__ __forceinline__ uint32_t mix32(uint32_t x) {   // lowbias32
  x ^= x >> 16; x *= 0x21f0aaadu;
  x ^= x >> 15; x *= 0x735a2d97u;
  x ^= x >> 15;
  return x;
}

// sample: u16 < 65536*sigm(z)  <=>  fma(h, 2^(-z*log2e), h) < 65536
__device__ __forceinline__ bool samp16(uint32_t h16, float z) {
  float q = __builtin_amdgcn_exp2f(-1.442695041f * z);
  float hf = (float)h16;
  return fmaf(hf, q, hf) < 65536.0f;
}
__device__ __forceinline__ float softplusf(float z) {
  float e = __builtin_amdgcn_exp2f(-1.442695041f * fabsf(z));
  return fmaxf(z, 0.0f) + log1pf(e);
}

// 16 bits -> 16 packed i8 {0,1} (4 u32): per nibble (n*0x204081)&0x01010101
__device__ __forceinline__ i32x4 expand16_i8(uint32_t hw) {
  union { i32x4 v; uint32_t u[4]; } r;
  r.u[0] = ((hw         & 0xFu) * 0x00204081u) & 0x01010101u;
  r.u[1] = (((hw >>  4) & 0xFu) * 0x00204081u) & 0x01010101u;
  r.u[2] = (((hw >>  8) & 0xFu) * 0x00204081u) & 0x01010101u;
  r.u[3] = (((hw >> 12) & 0xFu) * 0x00204081u) & 0x01010101u;
  return r.v;
}

// ---- W fp32 [D][H] -> WHq (h-image: granule g=(d>>4)*128+j holds 16 d as i8)
//                    -> WXq (x-image: [dt=d>>4][dl=d&15][j], 128 i8 rows) ----
__global__ __launch_bounds__(512) void k_prep(const float* __restrict__ W,
                                              signed char* __restrict__ WHq,
                                              signed char* __restrict__ WXq,
                                              float sInv) {
  unsigned idx = blockIdx.x * 512u + threadIdx.x;   // over D*H
  float v = W[idx];
  int q = (int)rintf(v * sInv);
  q = q > 127 ? 127 : (q < -127 ? -127 : q);
  unsigned d = idx >> 7, j = idx & 127u;
  WHq[((d >> 4) * 128u + j) * 16u + (d & 15u)] = (signed char)q;
  WXq[(d >> 4) * 2048u + (d & 15u) * 128u + j] = (signed char)q;
}

__global__ __launch_bounds__(512, 4) void k_rbm(const float* __restrict__ x,
                                                const signed char* __restrict__ WHq,
                                                const signed char* __restrict__ WXq,
                                                const float* __restrict__ bx,
                                                const float* __restrict__ bh,
                                                double* __restrict__ S,
                                                RbmKeys K, float sW) {
  __shared__ uint32_t xbits[16 * 132];     // 8.4 KB: 16 rows x 128 words (+4 pad)
  __shared__ unsigned short hb16[16 * 8];  // 256 B: 16 rows x 128 h-bits
  __shared__ double sred[8];

  const int t = threadIdx.x;
  const int l = t & 63;
  const int w = t >> 6;
  const int rs = l >> 4;
  const int l15 = l & 15;
  const unsigned bt8 = blockIdx.x * 8u;   // rows: lr<8 -> bt8+lr ; lr>=8 -> +8192

  const int rsw = rs >> 1;             // word-within-128bit select
  const int rsh = (rs & 1) * 16;       // half-word shift

  // wave w owns j-range [w*16, w*16+16) in the h-pass
  float bhv[4];
#pragma unroll
  for (int reg = 0; reg < 4; ++reg) bhv[reg] = bh[w * 16 + rs * 4 + reg];

  // ---------- P0: load x rows, pack bits, accumulate x.bx ----------
  {
    float vbx = 0.f;
#pragma unroll 1
    for (int q = 0; q < 2; ++q) {
      const int lr = w * 2 + q;
      const unsigned g = bt8 + (unsigned)(lr & 7) + (unsigned)((lr >> 3) << 13);
      const f32x4* xrow = (const f32x4*)(x + (size_t)g * DD);
#pragma unroll
      for (int it = 0; it < 16; ++it) {
        f32x4 v = xrow[it * 64 + l];
        f32x4 bv = *(const f32x4*)(bx + it * 256 + l * 4);
        vbx += v.x * bv.x + v.y * bv.y + v.z * bv.z + v.w * bv.w;
        uint32_t nib = (v.x != 0.f ? 1u : 0u) | (v.y != 0.f ? 2u : 0u) |
                       (v.z != 0.f ? 4u : 0u) | (v.w != 0.f ? 8u : 0u);
        uint32_t word = nib << (4 * (l & 7));
        word |= __shfl_xor(word, 1);
        word |= __shfl_xor(word, 2);
        word |= __shfl_xor(word, 4);
        if ((l & 7) == 0) xbits[lr * 132 + it * 8 + (l >> 3)] = word;
      }
    }
#pragma unroll
    for (int off = 32; off; off >>= 1) vbx += __shfl_xor(vbx, off);
    if (l == 0) sred[w] = (double)vbx;
    __syncthreads();
    if (t == 0) {
      double s = 0.0;
      for (int i = 0; i < 8; ++i) s += sred[i];
      atomicAdd(S + 0, s);
    }
  }

#pragma unroll 1
  for (int step = 0; step < 5; ++step) {
    // ===== h-pass: C^T[j][b], K=4096 over 32 c-iters of K=128 (2 i8 MFMAs) =====
    __syncthreads();   // previous x-pass xbits writes visible
    i32x4 acc0 = (i32x4){0, 0, 0, 0};
    i32x4 acc1 = (i32x4){0, 0, 0, 0};
#pragma unroll 2
    for (int c = 0; c < 32; ++c) {
      const u32x4 xw = *(const u32x4*)&xbits[l15 * 132 + c * 4];
      i32x4 bf0 = expand16_i8((xw[rsw] >> rsh) & 0xffffu);
      const i32x4 af0 = *(const i32x4*)(WHq +
          ((unsigned)(c * 8 + rs) * 128u + (unsigned)(w * 16 + l15)) * 16u);
      acc0 = __builtin_amdgcn_mfma_i32_16x16x64_i8(af0, bf0, acc0, 0, 0, 0);
      i32x4 bf1 = expand16_i8((xw[2 + rsw] >> rsh) & 0xffffu);
      const i32x4 af1 = *(const i32x4*)(WHq +
          ((unsigned)(c * 8 + 4 + rs) * 128u + (unsigned)(w * 16 + l15)) * 16u);
      acc1 = __builtin_amdgcn_mfma_i32_16x16x64_i8(af1, bf1, acc1, 0, 0, 0);
    }
    const i32x4 acc = acc0 + acc1;

    // ---------- h epilogue: sample h (steps 0-3) / energy (steps 0,4) ----------
    if (step < 4) {
      const uint32_t key = K.kh[step];
      const unsigned glow = bt8 + (unsigned)(l15 & 7);
      uint32_t mask = 0;
      float loc = 0.f;
#pragma unroll
      for (int reg = 0; reg < 4; ++reg) {
        const int jj = w * 16 + rs * 4 + reg;
        float z = fmaf((float)acc[reg], sW, bhv[reg]);
        if (step == 0) loc += softplusf(z);
        uint32_t h32 = mix32((glow * 128u + (unsigned)jj) ^ key);
        uint32_t h16 = (l15 >= 8) ? (h32 >> 16) : (h32 & 0xffffu);
        mask |= (samp16(h16, z) ? 1u : 0u) << (rs * 4 + reg);
      }
      mask |= __shfl_xor(mask, 16);
      mask |= __shfl_xor(mask, 32);
      if (rs == 0) hb16[l15 * 8 + w] = (unsigned short)mask;
      if (step == 0) {
#pragma unroll
        for (int off = 32; off; off >>= 1) loc += __shfl_xor(loc, off);
        if (l == 0) sred[w] = (double)loc;
      }
      __syncthreads();   // hb16 (and sred) visible
      if (step == 0 && t == 0) {
        double s = 0.0;
        for (int i = 0; i < 8; ++i) s += sred[i];
        atomicAdd(S + 0, s);
      }
    } else {
      float loc = 0.f;
#pragma unroll
      for (int reg = 0; reg < 4; ++reg)
        loc += softplusf(fmaf((float)acc[reg], sW, bhv[reg]));
#pragma unroll
      for (int off = 32; off; off >>= 1) loc += __shfl_xor(loc, off);
      if (l == 0) sred[w] = (double)loc;
      __syncthreads();
      if (t == 0) {
        double s = 0.0;
        for (int i = 0; i < 8; ++i) s += sred[i];
        atomicAdd(S + 1, s);
      }
    }

    // ==== x-pass: K=128 (2 i8 MFMAs/tile), barrier-free, hash-share via shfl ====
    if (step < 4) {
      const uint32_t key = K.kx[step];
      i32x4 bfr[2];   // h B-fragments (16 rows), whole pass
#pragma unroll
      for (int ch = 0; ch < 2; ++ch)
        bfr[ch] = expand16_i8(hb16[l15 * 8 + ch * 4 + rs]);
      float vbx1 = 0.f;
      const unsigned mrow = (bt8 + (unsigned)(l15 & 7)) * 4096u;
      const bool hi = (l15 >= 8);
      const int myrg = hi ? 1 : 0;
      const int myoff = hi ? 16 : 0;
#pragma unroll 1
      for (int dsub = 0; dsub < 16; ++dsub) {
        const int dbase = w * 512 + dsub * 32;
        uint32_t hmy[4], hoth[4];
#pragma unroll
        for (int reg = 0; reg < 4; ++reg) {
          const unsigned d = (unsigned)(dbase + myoff + rs * 4 + reg);
          hmy[reg] = mix32((mrow + d) ^ key);
        }
#pragma unroll
        for (int reg = 0; reg < 4; ++reg) hoth[reg] = __shfl_xor(hmy[reg], 8);
        uint32_t mm = 0;
#pragma unroll
        for (int rg = 0; rg < 2; ++rg) {
          i32x4 a = (i32x4){0, 0, 0, 0};
          const unsigned dt = (unsigned)(w * 32 + dsub * 2 + rg);
#pragma unroll
          for (int ch = 0; ch < 2; ++ch) {
            const i32x4 afv = *(const i32x4*)(WXq + dt * 2048u +
                (unsigned)l15 * 128u + (unsigned)(ch * 64 + rs * 16));
            a = __builtin_amdgcn_mfma_i32_16x16x64_i8(afv, bfr[ch], a, 0, 0, 0);
          }
          f32x4 bx4 = *(const f32x4*)(bx + dbase + rg * 16 + rs * 4);
#pragma unroll
          for (int reg = 0; reg < 4; ++reg) {
            const int pos = rg * 16 + rs * 4 + reg;
            const uint32_t h32 = (rg == myrg) ? hmy[reg] : hoth[reg];
            const uint32_t h16 = hi ? (h32 >> 16) : (h32 & 0xffffu);
            float z = fmaf((float)a[reg], sW, bx4[reg]);
            bool s = samp16(h16, z);
            mm |= (s ? 1u : 0u) << pos;
            if (step == 3 && s) vbx1 += bx4[reg];
          }
        }
        mm |= __shfl_xor(mm, 16);
        mm |= __shfl_xor(mm, 32);
        if (rs == 0) xbits[l15 * 132 + w * 16 + dsub] = mm;
      }
      if (step == 3) {
#pragma unroll
        for (int off = 32; off; off >>= 1) vbx1 += __shfl_xor(vbx1, off);
        if (l == 0) sred[w] = (double)vbx1;
        __syncthreads();
        if (t == 0) {
          double s = 0.0;
          for (int i = 0; i < 8; ++i) s += sred[i];
          atomicAdd(S + 1, s);
        }
      }
      // next h-pass begins with __syncthreads(), ordering these xbits writes
    }
  }
}

__global__ void k_final(const double* __restrict__ S, float* __restrict__ out) {
  if (threadIdx.x == 0 && blockIdx.x == 0)
    out[0] = (float)((S[1] - S[0]) / (double)BB);   // mean F(x) - mean F(x_rec)
}

extern "C" void kernel_launch(void* const* d_in, const int* in_sizes, int n_in,
                              void* d_out, int out_size, void* d_ws, size_t ws_size,
                              hipStream_t stream) {
  const float* x  = (const float*)d_in[0];
  const float* W  = (const float*)d_in[1];
  const float* bx = (const float*)d_in[2];
  const float* bh = (const float*)d_in[3];

  const size_t IMG = (size_t)DD * HH;   // 512 KB each (i8)
  if (ws_size < 2 * IMG + 64) return;

  signed char* WHq = (signed char*)d_ws;
  signed char* WXq = (signed char*)((char*)d_ws + IMG);
  double* S = (double*)((char*)d_ws + 2 * IMG);

  hipMemsetAsync(S, 0, 2 * sizeof(double), stream);

  RbmKeys K;
  for (int i = 0; i < 4; ++i) {
    uint32_t a, b;
    tf2x32_host(0u, 42u, 0u, (uint32_t)(2 * i), a, b);
    K.kh[i] = a ^ (b * 0x9E3779B9u);
    tf2x32_host(0u, 42u, 0u, (uint32_t)(2 * i + 1), a, b);
    K.kx[i] = a ^ (b * 0x9E3779B9u);
  }

  const float wlim = sqrtf(6.0f / (float)(DD + HH));  // glorot_uniform limit
  const float sW   = wlim / 127.0f;
  const float sInv = 127.0f / wlim;

  k_prep<<<(DD * HH) / 512, 512, 0, stream>>>(W, WHq, WXq, sInv);
  k_rbm<<<BB / 16, 512, 0, stream>>>(x, WHq, WXq, bx, bh, S, K, sW);
  k_final<<<1, 64, 0, stream>>>(S, (float*)d_out);
}